// Round 3
// baseline (1356.173 us; speedup 1.0000x reference)
//
#include <hip/hip_runtime.h>
#include <cfloat>
#include <math.h>

#define HH 56
#define WW 56
#define HW 3136          // 56*56
#define CHN 256

// ---------------------------------------------------------------------------
// Single fused kernel: channel-L2 norms + correlation volume (81 offsets) +
// argmax + collapsed softmax.
//
// Block = 576 threads = 9 waves; wave w owns dy row w (9 dx offsets).
// Lane: T=4 contiguous x-pixels -> acc[9][4] = 36 VGPRs (no spill).
// Channels staged 4 at a time through LDS.
//
// Bank conflicts (round-2 lesson): ds_read_b128 is serviced 8 lanes/cycle;
// conflict-free needs each consecutive-8-lane group to cover all 32 banks
// -> row stride must be ===16 mod 32 floats. xs stride 16, ps stride 48.
// (Round-2 strides 20/36 gave 4-way aliasing: 1.67e8 conflict cycles.)
//
// Norm fusion: the staging loads see every channel of both tiles, so we
// accumulate per-pixel sum(x^2) in fp64 during staging (fp64 => argmax
// matches the fp64 numpy reference; round-2 margin was 5.5e-22).
// Eliminates the separate norm kernel and its 205 MB of HBM reads.
// ---------------------------------------------------------------------------
__global__ __launch_bounds__(576, 6) void corr_kernel(const float* __restrict__ x,
                                                      float* __restrict__ out) {
    const int tile = blockIdx.x;   // 0..15
    const int b    = blockIdx.y;   // 0..63
    const int offs0 = tile & 3, offs1 = tile >> 2;
    // tile origins {0,16,32,40}: full coverage of 56 with overlap (idempotent)
    const int x0 = (offs0 < 3) ? offs0 * 16 : 40;
    const int y0 = (offs1 < 3) ? offs1 * 16 : 40;
    const int tid = threadIdx.x;
    float* outb = out + (size_t)b * 3 * HW;

    if ((b & 7) == 0) {
        // first frame of each segment: x_post == 0 -> r == 0 -> mot = 0, conf = 0
        if (tid < 256) {
            int g = (y0 + (tid >> 4)) * WW + x0 + (tid & 15);
            outb[g] = 0.f; outb[HW + g] = 0.f; outb[2 * HW + g] = 0.f;
        }
        return;
    }

    const int wave = tid >> 6;     // 0..8 == dy row
    const int lane = tid & 63;
    const int ty   = lane >> 2;    // 0..15 tile row
    const int tx4  = lane & 3;     // pixel group: x-local 4*tx4 .. 4*tx4+3

    __shared__ __align__(16) float xs[4 * 16 * 16];   // [ch][row][16]  stride 16 === 16 mod 32
    __shared__ __align__(16) float ps[4 * 24 * 48];   // [ch][row][48]  stride 48 === 16 mod 32
    __shared__ double ivq[24 * 25];                   // prev inv-norms (halo)
    __shared__ double ivp[256];                       // cur inv-norms
    __shared__ double csq[4 * 256];                   // cur sq-sum partials [chq][px]
    __shared__ unsigned long long red[256];           // packed argmax per pixel

    const float* xcur = x + (size_t)b * (CHN * HW);
    const float* xprv = x + (size_t)(b - 1) * (CHN * HW);

    if (tid < 256) red[tid] = 0ULL;

    // ps staging: 576 threads = 4ch x 24row x 6 col-quads (one float4 each)
    const int ch_s  = tid / 144;
    const int rem_s = tid - ch_s * 144;
    const int row_s = rem_s / 6;
    const int c4    = rem_s - row_s * 6;
    const int gy_s  = y0 - 4 + row_s;
    const int gx_s  = x0 - 4 + 4 * c4;
    const bool pval = (gy_s >= 0 && gy_s < HH && gx_s >= 0 && gx_s < WW); // quad never straddles
    const int    ps_l = (ch_s * 24 + row_s) * 48 + 4 * c4;
    const size_t ps_g = (size_t)ch_s * HW + (pval ? (gy_s * WW + gx_s) : 0);
    if (!pval) *(float4*)&ps[ps_l] = make_float4(0.f, 0.f, 0.f, 0.f);  // zero once, never rewritten

    // xs staging: threads 0..255 = 4ch x 16row x 4 col-quads
    int xs_l = 0; size_t xs_g = 0;
    if (tid < 256) {
        int chx = tid >> 6, r2 = tid & 63, sy = r2 >> 2, sx = r2 & 3;
        xs_l = (chx * 16 + sy) * 16 + 4 * sx;
        xs_g = (size_t)chx * HW + (size_t)(y0 + sy) * WW + x0 + 4 * sx;
    }

    float acc[9][4];
    #pragma unroll
    for (int j = 0; j < 9; ++j)
        #pragma unroll
        for (int t = 0; t < 4; ++t) acc[j][t] = 0.f;

    double psq0 = 0, psq1 = 0, psq2 = 0, psq3 = 0;   // prev-frame sq-sums (my 4 px, my ch quarter)
    double xsq0 = 0, xsq1 = 0, xsq2 = 0, xsq3 = 0;   // cur-frame sq-sums

    const float* xb = &xs[ty * 16 + 4 * tx4];
    const float* pb = &ps[(ty + wave) * 48 + 4 * tx4];

    for (int cc = 0; cc < 64; ++cc) {
        const size_t cb = (size_t)(cc * 4) * HW;
        __syncthreads();  // previous compute done before overwriting LDS
        if (pval) {
            float4 v = *(const float4*)(xprv + cb + ps_g);
            psq0 = fma((double)v.x, (double)v.x, psq0);
            psq1 = fma((double)v.y, (double)v.y, psq1);
            psq2 = fma((double)v.z, (double)v.z, psq2);
            psq3 = fma((double)v.w, (double)v.w, psq3);
            *(float4*)&ps[ps_l] = v;
        }
        if (tid < 256) {
            float4 v = *(const float4*)(xcur + cb + xs_g);
            xsq0 = fma((double)v.x, (double)v.x, xsq0);
            xsq1 = fma((double)v.y, (double)v.y, xsq1);
            xsq2 = fma((double)v.z, (double)v.z, xsq2);
            xsq3 = fma((double)v.w, (double)v.w, xsq3);
            *(float4*)&xs[xs_l] = v;
        }
        __syncthreads();
        #pragma unroll
        for (int ch = 0; ch < 4; ++ch) {
            float4 xq = *(const float4*)(xb + ch * 256);
            float4 w0 = *(const float4*)(pb + ch * 1152);
            float4 w1 = *(const float4*)(pb + ch * 1152 + 4);
            float4 w2 = *(const float4*)(pb + ch * 1152 + 8);
            float win[12] = { w0.x, w0.y, w0.z, w0.w,
                              w1.x, w1.y, w1.z, w1.w,
                              w2.x, w2.y, w2.z, w2.w };
            #pragma unroll
            for (int dx = 0; dx < 9; ++dx) {
                acc[dx][0] = fmaf(xq.x, win[dx + 0], acc[dx][0]);
                acc[dx][1] = fmaf(xq.y, win[dx + 1], acc[dx][1]);
                acc[dx][2] = fmaf(xq.z, win[dx + 2], acc[dx][2]);
                acc[dx][3] = fmaf(xq.w, win[dx + 3], acc[dx][3]);
            }
        }
    }

    // ---- fused norm reduction (ps LDS recycled as fp64 scratch) ----
    __syncthreads();                       // everyone done reading ps
    double* sq4 = (double*)ps;             // 2304 doubles == 18432 B == sizeof(ps)
    {
        double* dst = &sq4[ch_s * 576 + (row_s * 6 + c4) * 4];
        dst[0] = psq0; dst[1] = psq1; dst[2] = psq2; dst[3] = psq3;
    }
    if (tid < 256) {
        int chx = tid >> 6, r2 = tid & 63;
        double* dst = &csq[chx * 256 + (r2 >> 2) * 16 + (r2 & 3) * 4];
        dst[0] = xsq0; dst[1] = xsq1; dst[2] = xsq2; dst[3] = xsq3;
    }
    __syncthreads();
    {
        int row = tid / 24, col = tid - row * 24;   // 576 == 24*24 exactly
        int e = (row * 6 + (col >> 2)) * 4 + (col & 3);
        double s = sq4[e] + sq4[576 + e] + sq4[1152 + e] + sq4[1728 + e];
        // OOB halo px: s == 0 exactly -> inv = 1e12, but acc there is exactly 0 -> rv = 0. Matches ref.
        ivq[row * 25 + col] = 1.0 / fmax(sqrt(s), 1e-12);
    }
    if (tid < 256) {
        double s = csq[tid] + csq[256 + tid] + csq[512 + tid] + csq[768 + tid];
        ivp[tid] = 1.0 / fmax(sqrt(s), 1e-12);
    }
    __syncthreads();

    // ---- argmax epilogue: packed u64 (sortable key | 80-offset) + LDS atomicMax
    //      => exact first-max tie-break in flat (dy,dx) order ----
    const int px0 = ty * 16 + 4 * tx4;
    double ip[4];
    #pragma unroll
    for (int t = 0; t < 4; ++t) ip[t] = ivp[px0 + t];
    unsigned long long best[4] = { 0ULL, 0ULL, 0ULL, 0ULL };
    #pragma unroll
    for (int dx = 0; dx < 9; ++dx) {
        #pragma unroll
        for (int t = 0; t < 4; ++t) {
            double qv = ivq[(ty + wave) * 25 + 4 * tx4 + t + dx];
            float rv = (float)((double)acc[dx][t] * ip[t] * qv);
            unsigned int bits = __float_as_uint(rv);
            unsigned int key = (bits & 0x80000000u) ? ~bits : (bits | 0x80000000u);
            unsigned long long pk = ((unsigned long long)key << 32)
                                  | (unsigned int)(80 - (wave * 9 + dx));
            if (pk > best[t]) best[t] = pk;   // ascending dx + strict > == first-max
        }
    }
    #pragma unroll
    for (int t = 0; t < 4; ++t) atomicMax(&red[px0 + t], best[t]);
    __syncthreads();

    if (tid < 256) {
        unsigned long long pk = red[tid];
        int o = 80 - (int)(pk & 0xffffffffu);
        unsigned int key  = (unsigned int)(pk >> 32);
        unsigned int bits = (key & 0x80000000u) ? (key ^ 0x80000000u) : ~key;
        float v = __uint_as_float(bits);
        int oh = o / 9;
        float h_idx = (float)oh - 4.f;
        float v_idx = (float)(o - oh * 9) - 4.f;
        // gaussian(sigma=0.1) kills non-argmax cells below fp64-reference visibility
        // at our 8e-2 threshold: h_cord = h_idx * R/(R+1e-12), R = BETA * r_max
        float R  = 10.f * v;
        float pc = R / (R + 1e-12f);
        int g = (y0 + (tid >> 4)) * WW + x0 + (tid & 15);
        outb[g]          = h_idx * pc;
        outb[HW + g]     = v_idx * pc;
        outb[2 * HW + g] = v;
    }
}

extern "C" void kernel_launch(void* const* d_in, const int* in_sizes, int n_in,
                              void* d_out, int out_size, void* d_ws, size_t ws_size,
                              hipStream_t stream) {
    const float* x = (const float*)d_in[0];
    float* out = (float*)d_out;
    hipLaunchKernelGGL(corr_kernel, dim3(16, 64), dim3(576), 0, stream, x, out);
}

// Round 4
// 1048.991 us; speedup vs baseline: 1.2928x; 1.2928x over previous
//
#include <hip/hip_runtime.h>
#include <cfloat>
#include <math.h>

#define HH 56
#define WW 56
#define HW 3136          // 56*56
#define CHN 256

// ---------------------------------------------------------------------------
// Single fused kernel: channel-L2 norms + correlation volume (81 offsets) +
// argmax + collapsed softmax.
//
// Block = 576 threads = 9 waves; wave w owns dy row w (9 dx offsets).
// Lane: T=4 contiguous x-pixels -> acc[9][4] = 36 regs (AGPR-able, no spill).
// Channels staged 4 at a time through LDS (xs stride 16, ps stride 48).
//
// Round-3 lesson: fp64 sq-sum accumulators (16 VGPRs + v_fma_f64 in the
// staging path) spilled to scratch -> 1.07 GB writes, 744->1200 us. This
// round: fp32 quarter-partials (8 VGPRs, v_fmac_f32), combined in fp64 at
// the end. Matches np's own fp32 norm arithmetic more closely anyway.
// ---------------------------------------------------------------------------
__global__ __launch_bounds__(576, 6) void corr_kernel(const float* __restrict__ x,
                                                      float* __restrict__ out) {
    const int tile = blockIdx.x;   // 0..15
    const int b    = blockIdx.y;   // 0..63
    const int offs0 = tile & 3, offs1 = tile >> 2;
    // tile origins {0,16,32,40}: full coverage of 56 with overlap (idempotent)
    const int x0 = (offs0 < 3) ? offs0 * 16 : 40;
    const int y0 = (offs1 < 3) ? offs1 * 16 : 40;
    const int tid = threadIdx.x;
    float* outb = out + (size_t)b * 3 * HW;

    if ((b & 7) == 0) {
        // first frame of each segment: x_post == 0 -> r == 0 -> mot = 0, conf = 0
        if (tid < 256) {
            int g = (y0 + (tid >> 4)) * WW + x0 + (tid & 15);
            outb[g] = 0.f; outb[HW + g] = 0.f; outb[2 * HW + g] = 0.f;
        }
        return;
    }

    const int wave = tid >> 6;     // 0..8 == dy row
    const int lane = tid & 63;
    const int ty   = lane >> 2;    // 0..15 tile row
    const int tx4  = lane & 3;     // pixel group: x-local 4*tx4 .. 4*tx4+3

    __shared__ __align__(16) float xs[4 * 16 * 16];   // [ch][row][16]
    __shared__ __align__(16) float ps[4 * 24 * 48];   // [ch][row][48]
    __shared__ double ivq[24 * 25];                   // prev inv-norms (halo)
    __shared__ double ivp[256];                       // cur inv-norms
    __shared__ float  csq[4 * 256];                   // cur sq-sum partials [chq][px]
    __shared__ unsigned long long red[256];           // packed argmax per pixel

    const float* xcur = x + (size_t)b * (CHN * HW);
    const float* xprv = x + (size_t)(b - 1) * (CHN * HW);

    if (tid < 256) red[tid] = 0ULL;

    // ps staging: 576 threads = 4ch x 24row x 6 col-quads (one float4 each)
    const int ch_s  = tid / 144;
    const int rem_s = tid - ch_s * 144;
    const int row_s = rem_s / 6;
    const int c4    = rem_s - row_s * 6;
    const int gy_s  = y0 - 4 + row_s;
    const int gx_s  = x0 - 4 + 4 * c4;
    const bool pval = (gy_s >= 0 && gy_s < HH && gx_s >= 0 && gx_s < WW); // quad never straddles
    const int    ps_l = (ch_s * 24 + row_s) * 48 + 4 * c4;
    const size_t ps_g = (size_t)ch_s * HW + (pval ? (gy_s * WW + gx_s) : 0);
    if (!pval) *(float4*)&ps[ps_l] = make_float4(0.f, 0.f, 0.f, 0.f);  // zero once, never rewritten

    // xs staging: threads 0..255 = 4ch x 16row x 4 col-quads
    int xs_l = 0; size_t xs_g = 0;
    if (tid < 256) {
        int chx = tid >> 6, r2 = tid & 63, sy = r2 >> 2, sx = r2 & 3;
        xs_l = (chx * 16 + sy) * 16 + 4 * sx;
        xs_g = (size_t)chx * HW + (size_t)(y0 + sy) * WW + x0 + 4 * sx;
    }

    float acc[9][4];
    #pragma unroll
    for (int j = 0; j < 9; ++j)
        #pragma unroll
        for (int t = 0; t < 4; ++t) acc[j][t] = 0.f;

    // fp32 sq-sum partials (each thread: its 4 pixels, its 64-channel quarter)
    float psq0 = 0.f, psq1 = 0.f, psq2 = 0.f, psq3 = 0.f;
    float xsq0 = 0.f, xsq1 = 0.f, xsq2 = 0.f, xsq3 = 0.f;

    const float* xb = &xs[ty * 16 + 4 * tx4];
    const float* pb = &ps[(ty + wave) * 48 + 4 * tx4];

    for (int cc = 0; cc < 64; ++cc) {
        const size_t cb = (size_t)(cc * 4) * HW;
        __syncthreads();  // previous compute done before overwriting LDS
        if (pval) {
            float4 v = *(const float4*)(xprv + cb + ps_g);
            psq0 = fmaf(v.x, v.x, psq0);
            psq1 = fmaf(v.y, v.y, psq1);
            psq2 = fmaf(v.z, v.z, psq2);
            psq3 = fmaf(v.w, v.w, psq3);
            *(float4*)&ps[ps_l] = v;
        }
        if (tid < 256) {
            float4 v = *(const float4*)(xcur + cb + xs_g);
            xsq0 = fmaf(v.x, v.x, xsq0);
            xsq1 = fmaf(v.y, v.y, xsq1);
            xsq2 = fmaf(v.z, v.z, xsq2);
            xsq3 = fmaf(v.w, v.w, xsq3);
            *(float4*)&xs[xs_l] = v;
        }
        __syncthreads();
        #pragma unroll
        for (int ch = 0; ch < 4; ++ch) {
            float4 xq = *(const float4*)(xb + ch * 256);
            float4 w0 = *(const float4*)(pb + ch * 1152);
            float4 w1 = *(const float4*)(pb + ch * 1152 + 4);
            float4 w2 = *(const float4*)(pb + ch * 1152 + 8);
            float win[12] = { w0.x, w0.y, w0.z, w0.w,
                              w1.x, w1.y, w1.z, w1.w,
                              w2.x, w2.y, w2.z, w2.w };
            #pragma unroll
            for (int dx = 0; dx < 9; ++dx) {
                acc[dx][0] = fmaf(xq.x, win[dx + 0], acc[dx][0]);
                acc[dx][1] = fmaf(xq.y, win[dx + 1], acc[dx][1]);
                acc[dx][2] = fmaf(xq.z, win[dx + 2], acc[dx][2]);
                acc[dx][3] = fmaf(xq.w, win[dx + 3], acc[dx][3]);
            }
        }
    }

    // ---- fused norm reduction (ps LDS recycled as fp32 scratch) ----
    __syncthreads();                       // everyone done reading ps
    float* sq4 = (float*)ps;               // 2304 floats needed <= 4608 available
    {
        float* dst = &sq4[ch_s * 576 + (row_s * 6 + c4) * 4];
        dst[0] = psq0; dst[1] = psq1; dst[2] = psq2; dst[3] = psq3;
    }
    if (tid < 256) {
        int chx = tid >> 6, r2 = tid & 63;
        float* dst = &csq[chx * 256 + (r2 >> 2) * 16 + (r2 & 3) * 4];
        dst[0] = xsq0; dst[1] = xsq1; dst[2] = xsq2; dst[3] = xsq3;
    }
    __syncthreads();
    {
        int row = tid / 24, col = tid - row * 24;   // 576 == 24*24 exactly
        int e = (row * 6 + (col >> 2)) * 4 + (col & 3);
        double s = (double)sq4[e] + (double)sq4[576 + e]
                 + (double)sq4[1152 + e] + (double)sq4[1728 + e];
        // OOB halo px: s == 0 exactly -> inv = 1e12, but acc there is exactly 0 -> rv = 0.
        ivq[row * 25 + col] = 1.0 / fmax(sqrt(s), 1e-12);
    }
    if (tid < 256) {
        double s = (double)csq[tid] + (double)csq[256 + tid]
                 + (double)csq[512 + tid] + (double)csq[768 + tid];
        ivp[tid] = 1.0 / fmax(sqrt(s), 1e-12);
    }
    __syncthreads();

    // ---- argmax epilogue: packed u64 (sortable key | 80-offset) + LDS atomicMax
    //      => exact first-max tie-break in flat (dy,dx) order ----
    const int px0 = ty * 16 + 4 * tx4;
    double ip[4];
    #pragma unroll
    for (int t = 0; t < 4; ++t) ip[t] = ivp[px0 + t];
    unsigned long long best[4] = { 0ULL, 0ULL, 0ULL, 0ULL };
    #pragma unroll
    for (int dx = 0; dx < 9; ++dx) {
        #pragma unroll
        for (int t = 0; t < 4; ++t) {
            double qv = ivq[(ty + wave) * 25 + 4 * tx4 + t + dx];
            float rv = (float)((double)acc[dx][t] * ip[t] * qv);
            unsigned int bits = __float_as_uint(rv);
            unsigned int key = (bits & 0x80000000u) ? ~bits : (bits | 0x80000000u);
            unsigned long long pk = ((unsigned long long)key << 32)
                                  | (unsigned int)(80 - (wave * 9 + dx));
            if (pk > best[t]) best[t] = pk;   // ascending dx + strict > == first-max
        }
    }
    #pragma unroll
    for (int t = 0; t < 4; ++t) atomicMax(&red[px0 + t], best[t]);
    __syncthreads();

    if (tid < 256) {
        unsigned long long pk = red[tid];
        int o = 80 - (int)(pk & 0xffffffffu);
        unsigned int key  = (unsigned int)(pk >> 32);
        unsigned int bits = (key & 0x80000000u) ? (key ^ 0x80000000u) : ~key;
        float v = __uint_as_float(bits);
        int oh = o / 9;
        float h_idx = (float)oh - 4.f;
        float v_idx = (float)(o - oh * 9) - 4.f;
        // gaussian(sigma=0.1) kills non-argmax cells below threshold visibility:
        // h_cord = h_idx * R/(R+1e-12), R = BETA * r_max
        float R  = 10.f * v;
        float pc = R / (R + 1e-12f);
        int g = (y0 + (tid >> 4)) * WW + x0 + (tid & 15);
        outb[g]          = h_idx * pc;
        outb[HW + g]     = v_idx * pc;
        outb[2 * HW + g] = v;
    }
}

extern "C" void kernel_launch(void* const* d_in, const int* in_sizes, int n_in,
                              void* d_out, int out_size, void* d_ws, size_t ws_size,
                              hipStream_t stream) {
    const float* x = (const float*)d_in[0];
    float* out = (float*)d_out;
    hipLaunchKernelGGL(corr_kernel, dim3(16, 64), dim3(576), 0, stream, x, out);
}

// Round 5
// 1009.152 us; speedup vs baseline: 1.3439x; 1.0395x over previous
//
#include <hip/hip_runtime.h>
#include <cfloat>
#include <math.h>

#define HH 56
#define WW 56
#define HW 3136          // 56*56
#define CHN 256

// ---------------------------------------------------------------------------
// Fused: channel-L2 norms + correlation volume (81 offsets) + argmax +
// collapsed softmax.
//
// Block = 576 threads = 9 waves; wave w owns dy row w (9 dx offsets).
// Lane: T=4 contiguous x-pixels -> acc[9][4] = 36 regs.
//
// Round-5 structure (LDS-pipe-bound diagnosis):
//  - xq comes straight from GLOBAL (L1-served; 9 waves share a 4 KB/iter
//    working set) -> xs tile deleted: 12 instead of 16 ds_read_b128 per
//    wave-iter, no xs staging writes. vmem pipe runs parallel to LDS pipe.
//  - ps (prev-frame halo) double-buffered -> ONE __syncthreads per iter.
//  - launch_bounds (576,5): <=102 VGPR. Round-4's (576,6) was still
//    spilling ~2 dwords/thread-iter (WRITE_SIZE 325 MB).
//  - wave 0 sees all 256 channels of its 4 pixels via xq -> computes ivp
//    directly (csq reduction deleted).
// ---------------------------------------------------------------------------
__global__ __launch_bounds__(576, 5) void corr_kernel(const float* __restrict__ x,
                                                      float* __restrict__ out) {
    const int tile = blockIdx.x;   // 0..15
    const int b    = blockIdx.y;   // 0..63
    const int offs0 = tile & 3, offs1 = tile >> 2;
    // tile origins {0,16,32,40}: full coverage of 56 with overlap (idempotent)
    const int x0 = (offs0 < 3) ? offs0 * 16 : 40;
    const int y0 = (offs1 < 3) ? offs1 * 16 : 40;
    const int tid = threadIdx.x;
    float* outb = out + (size_t)b * 3 * HW;

    if ((b & 7) == 0) {
        // first frame of each segment: x_post == 0 -> r == 0 -> mot = 0, conf = 0
        if (tid < 256) {
            int g = (y0 + (tid >> 4)) * WW + x0 + (tid & 15);
            outb[g] = 0.f; outb[HW + g] = 0.f; outb[2 * HW + g] = 0.f;
        }
        return;
    }

    const int wave = tid >> 6;     // 0..8 == dy row
    const int lane = tid & 63;
    const int ty   = lane >> 2;    // 0..15 tile row
    const int tx4  = lane & 3;     // pixel group: x-local 4*tx4 .. 4*tx4+3

    __shared__ __align__(16) float ps[2][4 * 24 * 48];  // dbuf [ch][row][48]
    __shared__ double ivq[24 * 25];                     // prev inv-norms (halo)
    __shared__ double ivp[256];                         // cur inv-norms
    __shared__ unsigned long long red[256];             // packed argmax per pixel

    const float* xcur = x + (size_t)b * (CHN * HW);
    const float* xprv = x + (size_t)(b - 1) * (CHN * HW);

    if (tid < 256) red[tid] = 0ULL;

    // ps staging: 576 threads = 4ch x 24row x 6 col-quads (one float4 each)
    const int ch_s  = tid / 144;
    const int rem_s = tid - ch_s * 144;
    const int row_s = rem_s / 6;
    const int c4    = rem_s - row_s * 6;
    const int gy_s  = y0 - 4 + row_s;
    const int gx_s  = x0 - 4 + 4 * c4;
    const bool pval = (gy_s >= 0 && gy_s < HH && gx_s >= 0 && gx_s < WW); // quad never straddles
    const int ps_l  = (ch_s * 24 + row_s) * 48 + 4 * c4;
    const float* psrc = xprv + (size_t)ch_s * HW + (pval ? (gy_s * WW + gx_s) : 0);
    if (!pval) {
        // OOB pad quads: zero once in BOTH buffers, never rewritten
        *(float4*)&ps[0][ps_l] = make_float4(0.f, 0.f, 0.f, 0.f);
        *(float4*)&ps[1][ps_l] = make_float4(0.f, 0.f, 0.f, 0.f);
    }

    // per-lane global source for its 4 current-frame pixels
    const float* xq_base = xcur + (size_t)(y0 + ty) * WW + x0 + 4 * tx4;

    float acc[9][4];
    #pragma unroll
    for (int j = 0; j < 9; ++j)
        #pragma unroll
        for (int t = 0; t < 4; ++t) acc[j][t] = 0.f;

    float psq0 = 0.f, psq1 = 0.f, psq2 = 0.f, psq3 = 0.f;  // prev sq-sums (ch quarter)
    float xsq0 = 0.f, xsq1 = 0.f, xsq2 = 0.f, xsq3 = 0.f;  // cur sq-sums (wave 0: all ch)

    // prologue: stage chunk 0 into buffer 0
    if (pval) {
        float4 v = *(const float4*)psrc;
        psq0 = fmaf(v.x, v.x, psq0); psq1 = fmaf(v.y, v.y, psq1);
        psq2 = fmaf(v.z, v.z, psq2); psq3 = fmaf(v.w, v.w, psq3);
        *(float4*)&ps[0][ps_l] = v;
    }
    __syncthreads();

    const int pb_off = (ty + wave) * 48 + 4 * tx4;
    for (int cc = 0; cc < 64; ++cc) {
        // stage chunk cc+1 into the other buffer (no barrier needed: other buffer)
        if (cc < 63 && pval) {
            float4 v = *(const float4*)(psrc + (size_t)((cc + 1) * 4) * HW);
            psq0 = fmaf(v.x, v.x, psq0); psq1 = fmaf(v.y, v.y, psq1);
            psq2 = fmaf(v.z, v.z, psq2); psq3 = fmaf(v.w, v.w, psq3);
            *(float4*)&ps[(cc + 1) & 1][ps_l] = v;
        }
        const float* pbc = &ps[cc & 1][pb_off];
        #pragma unroll
        for (int ch = 0; ch < 4; ++ch) {
            float4 xq = *(const float4*)(xq_base + (size_t)(cc * 4 + ch) * HW);
            if (wave == 0) {
                xsq0 = fmaf(xq.x, xq.x, xsq0); xsq1 = fmaf(xq.y, xq.y, xsq1);
                xsq2 = fmaf(xq.z, xq.z, xsq2); xsq3 = fmaf(xq.w, xq.w, xsq3);
            }
            float4 w0 = *(const float4*)(pbc + ch * 1152);
            float4 w1 = *(const float4*)(pbc + ch * 1152 + 4);
            float4 w2 = *(const float4*)(pbc + ch * 1152 + 8);
            float win[12] = { w0.x, w0.y, w0.z, w0.w,
                              w1.x, w1.y, w1.z, w1.w,
                              w2.x, w2.y, w2.z, w2.w };
            #pragma unroll
            for (int dx = 0; dx < 9; ++dx) {
                acc[dx][0] = fmaf(xq.x, win[dx + 0], acc[dx][0]);
                acc[dx][1] = fmaf(xq.y, win[dx + 1], acc[dx][1]);
                acc[dx][2] = fmaf(xq.z, win[dx + 2], acc[dx][2]);
                acc[dx][3] = fmaf(xq.w, win[dx + 3], acc[dx][3]);
            }
        }
        __syncthreads();   // reads of buf[cc&1] done before iter cc+1 stages into it
    }

    // ---- norm reduction (ps LDS recycled as fp32 scratch) ----
    float* sq4 = &ps[0][0];                // 2304 floats needed, 9216 available
    {
        float* dst = &sq4[ch_s * 576 + (row_s * 6 + c4) * 4];
        dst[0] = psq0; dst[1] = psq1; dst[2] = psq2; dst[3] = psq3;
    }
    const int px0 = ty * 16 + 4 * tx4;
    if (wave == 0) {
        ivp[px0 + 0] = 1.0 / fmax(sqrt((double)xsq0), 1e-12);
        ivp[px0 + 1] = 1.0 / fmax(sqrt((double)xsq1), 1e-12);
        ivp[px0 + 2] = 1.0 / fmax(sqrt((double)xsq2), 1e-12);
        ivp[px0 + 3] = 1.0 / fmax(sqrt((double)xsq3), 1e-12);
    }
    __syncthreads();
    {
        int row = tid / 24, col = tid - row * 24;   // 576 == 24*24 exactly
        int e = (row * 6 + (col >> 2)) * 4 + (col & 3);
        double s = (double)sq4[e] + (double)sq4[576 + e]
                 + (double)sq4[1152 + e] + (double)sq4[1728 + e];
        // OOB halo px: s == 0 -> inv = 1e12, but acc there is exactly 0 -> rv = 0.
        ivq[row * 25 + col] = 1.0 / fmax(sqrt(s), 1e-12);
    }
    __syncthreads();

    // ---- argmax epilogue: packed u64 (sortable key | 80-offset) + LDS atomicMax
    //      => exact first-max tie-break in flat (dy,dx) order ----
    double ip[4];
    #pragma unroll
    for (int t = 0; t < 4; ++t) ip[t] = ivp[px0 + t];
    unsigned long long best[4] = { 0ULL, 0ULL, 0ULL, 0ULL };
    #pragma unroll
    for (int dx = 0; dx < 9; ++dx) {
        #pragma unroll
        for (int t = 0; t < 4; ++t) {
            double qv = ivq[(ty + wave) * 25 + 4 * tx4 + t + dx];
            float rv = (float)((double)acc[dx][t] * ip[t] * qv);
            unsigned int bits = __float_as_uint(rv);
            unsigned int key = (bits & 0x80000000u) ? ~bits : (bits | 0x80000000u);
            unsigned long long pk = ((unsigned long long)key << 32)
                                  | (unsigned int)(80 - (wave * 9 + dx));
            if (pk > best[t]) best[t] = pk;   // ascending dx + strict > == first-max
        }
    }
    #pragma unroll
    for (int t = 0; t < 4; ++t) atomicMax(&red[px0 + t], best[t]);
    __syncthreads();

    if (tid < 256) {
        unsigned long long pk = red[tid];
        int o = 80 - (int)(pk & 0xffffffffu);
        unsigned int key  = (unsigned int)(pk >> 32);
        unsigned int bits = (key & 0x80000000u) ? (key ^ 0x80000000u) : ~key;
        float v = __uint_as_float(bits);
        int oh = o / 9;
        float h_idx = (float)oh - 4.f;
        float v_idx = (float)(o - oh * 9) - 4.f;
        // gaussian(sigma=0.1) kills non-argmax cells below threshold visibility:
        // h_cord = h_idx * R/(R+1e-12), R = BETA * r_max
        float R  = 10.f * v;
        float pc = R / (R + 1e-12f);
        int g = (y0 + (tid >> 4)) * WW + x0 + (tid & 15);
        outb[g]          = h_idx * pc;
        outb[HW + g]     = v_idx * pc;
        outb[2 * HW + g] = v;
    }
}

extern "C" void kernel_launch(void* const* d_in, const int* in_sizes, int n_in,
                              void* d_out, int out_size, void* d_ws, size_t ws_size,
                              hipStream_t stream) {
    const float* x = (const float*)d_in[0];
    float* out = (float*)d_out;
    hipLaunchKernelGGL(corr_kernel, dim3(16, 64), dim3(576), 0, stream, x, out);
}